// Round 1
// baseline (544.395 us; speedup 1.0000x reference)
//
#include <hip/hip_runtime.h>
#include <hip/hip_bf16.h>

typedef __bf16 bf16x8 __attribute__((ext_vector_type(8)));
typedef float  f32x16 __attribute__((ext_vector_type(16)));
typedef float  f32x4  __attribute__((ext_vector_type(4)));

#define NODES 500000
#define BM    128

// ---------------------------------------------------------------------------
// Prep: pack Wcat[160][128] (Wx over k<128, Wh over k>=128) into bf16 MFMA
// B-fragment order: Bpack[((kk*4+g)*64 + lane)*8 + j] = Wcat[kk*16+(lane>>5)*8+j][g*32+(lane&31)]
// Also bias_cat[j] = bx[j] + bh[j] + b_gate[j]  (flat [4][32]).
// ---------------------------------------------------------------------------
__global__ __launch_bounds__(256) void prep_kernel(
    const float* __restrict__ Wx, const float* __restrict__ Wh,
    const float* __restrict__ bx, const float* __restrict__ bh,
    const float* __restrict__ bg,
    __bf16* __restrict__ Bpack, float* __restrict__ bias_cat)
{
  int t = threadIdx.x;
  for (int i = t; i < 20480; i += 256) {
    int j  = i & 7;
    int l  = (i >> 3) & 63;
    int g  = (i >> 9) & 3;
    int kk = i >> 11;
    int k   = kk * 16 + (l >> 5) * 8 + j;
    int col = l & 31;
    float v = (k < 128) ? Wx[(g * 128 + k) * 32 + col]
                        : Wh[(g * 32 + (k - 128)) * 32 + col];
    Bpack[i] = (__bf16)v;   // RNE
  }
  if (t < 128) bias_cat[t] = bx[t] + bh[t] + bg[t];
}

// ---------------------------------------------------------------------------
// Main fused kernel: 256 thr / 4 waves, BM=128 rows per block.
// Wave w computes rows [32w,32w+32) x all 128 cols (4 gates) via
// mfma_f32_32x32x16_bf16, 2-pass (x split hi/lo bf16; W single bf16).
// ---------------------------------------------------------------------------
__global__ __launch_bounds__(256, 2) void gconv_lstm_kernel(
    const float* __restrict__ x, const float* __restrict__ hin,
    const float* __restrict__ cin,
    const __bf16* __restrict__ Bpack, const float* __restrict__ bias_cat,
    const float* __restrict__ w_peep, const float* __restrict__ Wlin,
    const float* __restrict__ blin,
    float* __restrict__ out, float* __restrict__ hn_out, float* __restrict__ cn_out)
{
  __shared__ float Xs[128 * 128];   // 64 KB, XOR-swizzled 16B chunks
  __shared__ float Hs[128 * 32];    // 16 KB, XOR-swizzled 16B chunks

  const int t   = threadIdx.x;
  const int l   = t & 63;
  const int wid = t >> 6;
  const int rowbase = blockIdx.x * BM;

  const int rm   = l & 31;   // MFMA m (A row) and n (C col) lane index
  const int hf   = l >> 5;   // lane half
  const int colh = rm;       // H-column this lane owns in C layout

  // ---- stage X tile: content Xs[row][chunk c] holds x[row][c ^ (row&31)] ----
  const f32x4* xg  = (const f32x4*)x;
  f32x4*       Xs4 = (f32x4*)Xs;
  #pragma unroll
  for (int cc = 0; cc < 16; cc++) {
    int id  = cc * 256 + t;
    int row = id >> 5, ch = id & 31;
    int sr  = rowbase + row; sr = sr < NODES ? sr : NODES - 1;
    f32x4 v = xg[sr * 32 + ch];
    Xs4[row * 32 + (ch ^ (row & 31))] = v;
  }
  // ---- stage H tile (8 chunks/row, swizzle with row&7) ----
  const f32x4* hg  = (const f32x4*)hin;
  f32x4*       Hs4 = (f32x4*)Hs;
  #pragma unroll
  for (int cc = 0; cc < 4; cc++) {
    int id  = cc * 256 + t;
    int row = id >> 3, ch = id & 7;
    int sr  = rowbase + row; sr = sr < NODES ? sr : NODES - 1;
    f32x4 v = hg[sr * 8 + ch];
    Hs4[row * 8 + (ch ^ (row & 7))] = v;
  }

  // ---- prefetch c for the epilogue (C-layout addressing, coalesced 128B) ----
  float cv[16];
  #pragma unroll
  for (int r = 0; r < 16; r++) {
    int rowg = rowbase + 32 * wid + (r & 3) + 8 * (r >> 2) + 4 * hf;
    rowg = rowg < NODES ? rowg : NODES - 1;
    cv[r] = cin[rowg * 32 + colh];
  }
  float wp0 = w_peep[colh], wp1 = w_peep[32 + colh], wp2 = w_peep[64 + colh];

  // ---- accumulators, pre-seeded with fused bias (per-column) ----
  f32x16 acc[4];
  #pragma unroll
  for (int g = 0; g < 4; g++) {
    float b = bias_cat[g * 32 + colh];
    #pragma unroll
    for (int r = 0; r < 16; r++) acc[g][r] = b;
  }

  __syncthreads();

  const bf16x8* Bp = (const bf16x8*)Bpack;
  const int xs_base = (32 * wid + rm) * 32;  // f32x4 units
  const int hs_base = (32 * wid + rm) * 8;

#define DO_K(U0, U1, KK)                                                        \
  {                                                                             \
    bf16x8 ah, al;                                                              \
    _Pragma("unroll")                                                           \
    for (int j = 0; j < 8; j++) {                                               \
      float v   = (j < 4) ? (U0)[j] : (U1)[j - 4];                              \
      __bf16 bh_ = (__bf16)v;                                                   \
      ah[j] = bh_;                                                              \
      al[j] = (__bf16)(v - (float)bh_);                                         \
    }                                                                           \
    _Pragma("unroll")                                                           \
    for (int g = 0; g < 4; g++) {                                               \
      bf16x8 bf = Bp[((KK) * 4 + g) * 64 + l];                                  \
      acc[g] = __builtin_amdgcn_mfma_f32_32x32x16_bf16(ah, bf, acc[g], 0, 0, 0);\
      acc[g] = __builtin_amdgcn_mfma_f32_32x32x16_bf16(al, bf, acc[g], 0, 0, 0);\
    }                                                                           \
  }

  // K = 0..127 from X
  #pragma unroll 2
  for (int kk = 0; kk < 8; kk++) {
    int C0 = kk * 4 + hf * 2;
    f32x4 u0 = Xs4[xs_base + ( C0      ^ rm)];
    f32x4 u1 = Xs4[xs_base + ((C0 + 1) ^ rm)];
    DO_K(u0, u1, kk)
  }
  // K = 128..159 from H
  #pragma unroll
  for (int kk = 8; kk < 10; kk++) {
    int C0 = (kk - 8) * 4 + hf * 2;
    f32x4 u0 = Hs4[hs_base + ( C0      ^ (rm & 7))];
    f32x4 u1 = Hs4[hs_base + ((C0 + 1) ^ (rm & 7))];
    DO_K(u0, u1, kk)
  }
#undef DO_K

  // ---- gate math (exact fp32), store h_new / c_new ----
  float rhn[16];
  #pragma unroll
  for (int r = 0; r < 16; r++) {
    float pi = acc[0][r] + wp0 * cv[r];
    float pf = acc[1][r] + wp1 * cv[r];
    float pc = acc[2][r];
    float po = acc[3][r];
    float ig = 1.f / (1.f + __expf(-pi));
    float fg = 1.f / (1.f + __expf(-pf));
    float tg = 1.f - 2.f / (1.f + __expf(2.f * pc));
    float cn = fg * cv[r] + ig * tg;
    float og = 1.f / (1.f + __expf(-(po + wp2 * cn)));
    float hn = og * (1.f - 2.f / (1.f + __expf(2.f * cn)));
    int rowg = rowbase + 32 * wid + (r & 3) + 8 * (r >> 2) + 4 * hf;
    if (rowg < NODES) {
      cn_out[rowg * 32 + colh] = cn;
      hn_out[rowg * 32 + colh] = hn;
    }
    rhn[r] = hn > 0.f ? hn : 0.f;
  }

  __syncthreads();   // all waves done reading Xs/Hs — safe to overlay

  // ---- transpose relu(h_new) into LDS [128][33] + stage Wlin/blin ----
  float* hn_s = Xs;            // 128*33 floats, fits in Xs region
  float* wl_s = Hs;            // 297 floats, fits in Hs region
  #pragma unroll
  for (int r = 0; r < 16; r++) {
    int rl = 32 * wid + (r & 3) + 8 * (r >> 2) + 4 * hf;
    hn_s[rl * 33 + colh] = rhn[r];
  }
  for (int i = t; i < 297; i += 256)
    wl_s[i] = (i < 288) ? Wlin[i] : blin[i - 288];

  __syncthreads();

  // ---- head: out[row, 0..8] = relu(h_new) @ Wlin + blin (2 threads/row) ----
  {
    int rl   = t >> 1;
    int rowg = rowbase + rl;
    int jb   = (t & 1) ? 5 : 0;
    float o9[5];
    #pragma unroll
    for (int j = 0; j < 5; j++) o9[j] = wl_s[288 + jb + j];  // blin (j=9 reads scratch, discarded)
    #pragma unroll 4
    for (int cc = 0; cc < 32; cc++) {
      float v = hn_s[rl * 33 + cc];
      #pragma unroll
      for (int j = 0; j < 5; j++)
        o9[j] = fmaf(v, wl_s[cc * 9 + jb + j], o9[j]);
    }
    if (rowg < NODES) {
      #pragma unroll
      for (int j = 0; j < 5; j++)
        if (jb + j < 9) out[rowg * 9 + jb + j] = o9[j];
    }
  }
}

extern "C" void kernel_launch(void* const* d_in, const int* in_sizes, int n_in,
                              void* d_out, int out_size, void* d_ws, size_t ws_size,
                              hipStream_t stream) {
  const float* x  = (const float*)d_in[0];
  // d_in[1] edge_index (int64) and d_in[2] edge_weight are unused: ChebConv K=1.
  const float* h  = (const float*)d_in[3];
  const float* c  = (const float*)d_in[4];
  const float* Wx = (const float*)d_in[5];
  const float* bx = (const float*)d_in[6];
  const float* Wh = (const float*)d_in[7];
  const float* bh = (const float*)d_in[8];
  const float* wp = (const float*)d_in[9];
  const float* bg = (const float*)d_in[10];
  const float* Wl = (const float*)d_in[11];
  const float* bl = (const float*)d_in[12];

  __bf16* Bpack   = (__bf16*)d_ws;                       // 20480 bf16 = 40 KB
  float* bias_cat = (float*)((char*)d_ws + 20480 * 2);   // 128 f32

  float* out = (float*)d_out;
  float* hn  = out + (size_t)NODES * 9;
  float* cn  = hn + (size_t)NODES * 32;

  hipLaunchKernelGGL(prep_kernel, dim3(1), dim3(256), 0, stream,
                     Wx, Wh, bx, bh, bg, Bpack, bias_cat);

  int nblocks = (NODES + BM - 1) / BM;   // 3907
  hipLaunchKernelGGL(gconv_lstm_kernel, dim3(nblocks), dim3(256), 0, stream,
                     x, h, c, Bpack, bias_cat, wp, Wl, bl, out, hn, cn);
}